// Round 3
// baseline (623.388 us; speedup 1.0000x reference)
//
#include <hip/hip_runtime.h>

// ---------------------------------------------------------------------------
// SelfInteraction, fully fused: one persistent kernel, 32 rows/block.
// fp16 hi/lo split-precision MFMA (products AhBh + AhBl + AlBh).
// State (s,v f32) + A-operand buffers live in LDS (160 KiB exactly).
// Weights: pre-split 2-seg [col][hi(K)|lo(K)] f16, loaded global->VGPR as
// B-fragments (L2-resident, shared by all blocks). No barriers in K-loops.
// LDS A-rows xor-swizzled (blk ^= row&7) to kill ds_read_b128 conflicts.
// ---------------------------------------------------------------------------

typedef _Float16 half8 __attribute__((ext_vector_type(8)));
typedef float floatx4 __attribute__((ext_vector_type(4)));

#define RB   32
#define NTHR 512

static inline int cdiv_h(int a, int b){ return (a + b - 1) / b; }

__device__ __forceinline__ int swzA(int row, int h){   // row width 768 halves
  return row*768 + (((h>>3) ^ (row&7))<<3) + (h&7);
}
__device__ __forceinline__ int swzV(int row, int h){   // row width 512 halves
  return row*512 + (((h>>3) ^ (row&7))<<3) + (h&7);
}
__device__ __forceinline__ void split2(float v, _Float16* hi, _Float16* lo){
  _Float16 h = (_Float16)v; *hi = h; *lo = (_Float16)(v - (float)h);
}
__device__ __forceinline__ float red16(float x){       // sum over 16-lane group
  x += __shfl_xor(x, 1, 64); x += __shfl_xor(x, 2, 64);
  x += __shfl_xor(x, 4, 64); x += __shfl_xor(x, 8, 64);
  return x;
}

// K-loop: A from swizzled LDS, B fragments straight from global (L2-hot).
// Per chunk cc: 3 compensated products; B_hi reused for Ah and Al.
template<int NSC, int NT, int ROWW>
__device__ __forceinline__ void gemm_core(const _Float16* sAp,
                                          const _Float16* __restrict__ B,
                                          int colbase, floatx4 (&acc)[2][NT],
                                          int r, int kg){
  const int KB  = NSC*32;
  const int LDB = 2*KB;
  const _Float16* bb = B + (size_t)(colbase + r)*LDB + (size_t)kg*8;
  const int rx = r & 7;
  #pragma unroll
  for (int cc = 0; cc < NSC; ++cc){
    half8 ah[2], al[2], bh[NT], bl[NT];
    #pragma unroll
    for (int mt = 0; mt < 2; ++mt){
      const int row = mt*16 + r;
      const int ohi = (((cc*4 + kg)        ^ rx) << 3);
      const int olo = (((NSC*4 + cc*4 + kg) ^ rx) << 3);
      ah[mt] = *(const half8*)(sAp + row*ROWW + ohi);
      al[mt] = *(const half8*)(sAp + row*ROWW + olo);
    }
    #pragma unroll
    for (int nt = 0; nt < NT; ++nt){
      bh[nt] = *(const half8*)(bb + (size_t)nt*16*LDB + cc*32);
      bl[nt] = *(const half8*)(bb + (size_t)nt*16*LDB + KB + cc*32);
    }
    #pragma unroll
    for (int mt = 0; mt < 2; ++mt)
      #pragma unroll
      for (int nt = 0; nt < NT; ++nt){
        acc[mt][nt] = __builtin_amdgcn_mfma_f32_16x16x32_f16(ah[mt], bh[nt], acc[mt][nt], 0, 0, 0);
        acc[mt][nt] = __builtin_amdgcn_mfma_f32_16x16x32_f16(ah[mt], bl[nt], acc[mt][nt], 0, 0, 0);
        acc[mt][nt] = __builtin_amdgcn_mfma_f32_16x16x32_f16(al[mt], bh[nt], acc[mt][nt], 0, 0, 0);
      }
  }
}

// ---------------------------- weight prep ----------------------------------
// 2-seg split layout per tensor: o[col*2K + k] = hi, o[col*2K + K + k] = lo.
// Per-layer base: W1' 0 (384x768), W2' 294912 (640x768), W0' 786432 (128x768),
// WV' 884736 (128x512); layer stride 950272 halves.
__global__ __launch_bounds__(256) void prep_all2(const float* __restrict__ w1,
                                                 const float* __restrict__ w2,
                                                 const float* __restrict__ w0,
                                                 const float* __restrict__ wv,
                                                 _Float16* __restrict__ W){
  int idx = blockIdx.x*256 + threadIdx.x;
  const int P = 475136;
  if (idx >= 2*P) return;
  int l = (idx >= P) ? 1 : 0;
  int t = idx - l*P;
  const float RS384 = 0.051031036307982884f;    // 1/sqrt(384)
  _Float16* base = W + (size_t)l*950272;
  const float* w; int K, ldw, col, k; float scale; _Float16* o;
  if (t < 147456){ col = t/384; k = t - col*384;
    w = w1 + (size_t)l*147456; K=384; ldw=384; scale=RS384; o = base; }
  else if (t < 393216){ int u = t-147456; col = u/384; k = u - col*384;
    w = w2 + (size_t)l*294912; K=384; ldw=768; scale=RS384; o = base + 294912; }
  else if (t < 442368){ int u = t-393216; col = u/384; k = u - col*384;
    w = w0 + (size_t)l*49152; K=384; ldw=128; scale=RS384; o = base + 786432; }
  else { int u = t-442368; col = u/256; k = u - col*256;
    w = wv + (size_t)l*32768; K=256; ldw=128; scale=0.0625f; o = base + 884736; }
  float v = w[(size_t)k*ldw + col] * scale;
  _Float16 hi = (_Float16)v;
  size_t b = (size_t)col*2*K + k;
  o[b]     = hi;
  o[b + K] = (_Float16)(v - (float)hi);
}

// ---------------------------- fused kernel ---------------------------------
__global__ __launch_bounds__(NTHR, 2) void fused(const float* __restrict__ x,
                                                 const _Float16* __restrict__ W,
                                                 const float* __restrict__ g0,
                                                 const float* __restrict__ g1,
                                                 float* __restrict__ out){
  extern __shared__ char lds[];
  float*    sS = (float*)lds;                        // 32x128 f32 = 16 KB
  float*    sV = (float*)(lds + 16384);              // 32x[d][ch] f32 = 48 KB
  _Float16* sA = (_Float16*)(lds + 65536);           // 32x768 halves = 48 KB
  _Float16* sB = (_Float16*)(lds + 114688);          // 32x768 halves = 48 KB
  float* OSf = (float*)sB;                           // reuse in P6/P7
  float* OVf = (float*)sA;

  const int tid  = threadIdx.x;
  const int wave = tid >> 6, lane = tid & 63;
  const int r = lane & 15, kg = lane >> 4;
  const int row0 = blockIdx.x * RB;

  // P0: load 32 rows of x -> sS, sV (v stored d-major: [row][d][ch])
  #pragma unroll
  for (int it = 0; it < 32; ++it){
    int flat = it*NTHR + tid;
    int n = flat >> 9, j = flat & 511;
    float val = x[(size_t)(row0 + n)*512 + j];
    if (j < 128) sS[n*128 + j] = val;
    else { int jj = j - 128; int ch = jj/3; int d = jj - ch*3;
           sV[n*384 + d*128 + ch] = val; }
  }
  __syncthreads();

  for (int l = 0; l < 2; ++l){
    const _Float16* Wl  = W + (size_t)l*950272;
    const _Float16* W1p = Wl;
    const _Float16* W2p = Wl + 294912;
    const _Float16* W0p = Wl + 786432;
    const _Float16* WVp = Wl + 884736;

    // P1: build sc' = [s, s^2, |v|^2/sqrt3] split hi/lo -> sA
    {
      const int row = tid >> 4, j = tid & 15;
      #pragma unroll
      for (int q = 0; q < 24; ++q){
        int c = j + q*16;
        float val;
        if (c < 128) val = sS[row*128 + c];
        else if (c < 256){ float s = sS[row*128 + c - 128]; val = s*s; }
        else {
          int ch = c - 256;
          float a = sV[row*384 + ch], b = sV[row*384 + 128 + ch],
                d2 = sV[row*384 + 256 + ch];
          val = (a*a + b*b + d2*d2) * 0.5773502691896258f;
        }
        split2(val, &sA[swzA(row, c)], &sA[swzA(row, 384 + c)]);
      }
    }
    __syncthreads();

    // P2: GEMM1 (h = silu(sc @ w1')), epilogue split -> sB
    {
      floatx4 acc[2][3];
      #pragma unroll
      for (int a = 0; a < 2; ++a)
        #pragma unroll
        for (int b = 0; b < 3; ++b) acc[a][b] = (floatx4){0.f,0.f,0.f,0.f};
      gemm_core<12,3,768>(sA, W1p, wave*48, acc, r, kg);
      #pragma unroll
      for (int mt = 0; mt < 2; ++mt)
        #pragma unroll
        for (int nt = 0; nt < 3; ++nt)
          #pragma unroll
          for (int i = 0; i < 4; ++i){
            int row = mt*16 + kg*4 + i;
            int col = wave*48 + nt*16 + r;
            float v = acc[mt][nt][i];
            float h = v / (1.0f + __expf(-v));
            split2(h, &sB[swzA(row, col)], &sB[swzA(row, 384 + col)]);
          }
    }
    __syncthreads();

    // P3: GEMM2 (g = h @ w2'), g stays in registers
    floatx4 accg[2][5];
    #pragma unroll
    for (int a = 0; a < 2; ++a)
      #pragma unroll
      for (int b = 0; b < 5; ++b) accg[a][b] = (floatx4){0.f,0.f,0.f,0.f};
    gemm_core<12,5,768>(sB, W2p, wave*80, accg, r, kg);

    // gated sc' in place on sA (exclusive per lane; sA not read during GEMM2)
    #pragma unroll
    for (int mt = 0; mt < 2; ++mt)
      #pragma unroll
      for (int nt = 0; nt < 5; ++nt)
        #pragma unroll
        for (int i = 0; i < 4; ++i){
          int col = wave*80 + nt*16 + r;
          if (col < 384){
            int row = mt*16 + kg*4 + i;
            int ih = swzA(row, col), il = swzA(row, 384 + col);
            float sc = (float)sA[ih] + (float)sA[il];
            split2(sc * accg[mt][nt][i], &sA[ih], &sA[il]);
          }
        }
    __syncthreads();

    // GEMM3: OS = gated sc' @ w0'
    floatx4 acc0[2][1];
    acc0[0][0] = (floatx4){0.f,0.f,0.f,0.f};
    acc0[1][0] = (floatx4){0.f,0.f,0.f,0.f};
    gemm_core<12,1,768>(sA, W0p, wave*16, acc0, r, kg);

    // vec path: per d, build A4_d = (vec * g_v) split -> sB, then GEMMv_d
    floatx4 accv[3][2][1];
    #pragma unroll
    for (int d = 0; d < 3; ++d){
      accv[d][0][0] = (floatx4){0.f,0.f,0.f,0.f};
      accv[d][1][0] = (floatx4){0.f,0.f,0.f,0.f};
    }
    for (int d = 0; d < 3; ++d){
      #pragma unroll
      for (int mt = 0; mt < 2; ++mt)
        #pragma unroll
        for (int nt = 0; nt < 5; ++nt)
          #pragma unroll
          for (int i = 0; i < 4; ++i){
            int col = wave*80 + nt*16 + r;
            if (col >= 384){
              int row = mt*16 + kg*4 + i;
              int mm = col - 384, ch = mm & 127;
              float smul = (mm >= 128) ? 1.4142135623730951f * sS[row*128 + ch] : 1.0f;
              float val = sV[row*384 + d*128 + ch] * smul * accg[mt][nt][i];
              split2(val, &sB[swzV(row, mm)], &sB[swzV(row, 256 + mm)]);
            }
          }
      __syncthreads();
      gemm_core<8,1,512>(sB, WVp, wave*16, accv[d], r, kg);
      __syncthreads();
    }

    // P6: dump OS, OV accumulators to f32 LDS (sB, sA now free)
    #pragma unroll
    for (int mt = 0; mt < 2; ++mt)
      #pragma unroll
      for (int i = 0; i < 4; ++i){
        int row = mt*16 + kg*4 + i;
        int col = wave*16 + r;
        OSf[row*128 + col] = acc0[mt][0][i];
        #pragma unroll
        for (int d = 0; d < 3; ++d)
          OVf[row*384 + d*128 + col] = accv[d][mt][0][i];
      }
    __syncthreads();

    // P7: residual + (layer0: eq-layernorm back to state | layer1: output)
    {
      const int row = tid >> 4, j = tid & 15;
      float sv_[8], vv_[24];
      float ssum = 0.f;
      #pragma unroll
      for (int q = 0; q < 8; ++q){
        int c = j + q*16;
        sv_[q] = sS[row*128 + c] + OSf[row*128 + c];
        ssum += sv_[q];
      }
      #pragma unroll
      for (int q = 0; q < 24; ++q){
        int e = j + q*16;
        vv_[q] = sV[row*384 + e] + OVf[row*384 + e];
      }
      if (l == 0){
        float mu = red16(ssum) * (1.0f/128.0f);
        float var = 0.f;
        #pragma unroll
        for (int q = 0; q < 8; ++q){ float d = sv_[q] - mu; var += d*d; }
        var = red16(var) * (1.0f/128.0f);
        float sd = sqrtf(var + 1e-6f);
        float v2 = 0.f;
        #pragma unroll
        for (int q = 0; q < 24; ++q) v2 += vv_[q]*vv_[q];
        float rms = sqrtf(red16(v2) * (1.0f/384.0f) + 1e-6f);
        #pragma unroll
        for (int q = 0; q < 8; ++q){
          int c = j + q*16;
          sS[row*128 + c] = (sv_[q] - mu) / sd * g0[c];
        }
        #pragma unroll
        for (int q = 0; q < 24; ++q){
          int e = j + q*16;
          sV[row*384 + e] = vv_[q] / rms * g1[e & 127];
        }
      } else {
        size_t ob = (size_t)(row0 + row)*512;
        #pragma unroll
        for (int q = 0; q < 8; ++q){
          int c = j + q*16;
          out[ob + c] = sv_[q];
        }
        #pragma unroll
        for (int q = 0; q < 24; ++q){
          int e = j + q*16;
          int d = e >> 7, ch = e & 127;
          out[ob + 128 + ch*3 + d] = vv_[q];
        }
      }
    }
    __syncthreads();
  }
}

// ---------------------------- host launcher --------------------------------

extern "C" void kernel_launch(void* const* d_in, const int* in_sizes, int n_in,
                              void* d_out, int out_size, void* d_ws, size_t ws_size,
                              hipStream_t stream){
  const float* x  = (const float*)d_in[0];
  const float* w1 = (const float*)d_in[1];
  const float* w2 = (const float*)d_in[2];
  const float* w0 = (const float*)d_in[3];
  const float* wv = (const float*)d_in[4];
  const float* g0 = (const float*)d_in[5];
  const float* g1 = (const float*)d_in[6];
  float* out = (float*)d_out;
  const int N = in_sizes[0] / 512;                 // 16384

  _Float16* W = (_Float16*)d_ws;                   // 2 x 950272 halves = 3.8 MB

  prep_all2<<<cdiv_h(950272,256),256,0,stream>>>(w1, w2, w0, wv, W);
  fused<<<N/RB, NTHR, 163840, stream>>>(x, W, g0, g1, out);
}

// Round 4
// 590.828 us; speedup vs baseline: 1.0551x; 1.0551x over previous
//
#include <hip/hip_runtime.h>

// ---------------------------------------------------------------------------
// SelfInteraction, fully fused persistent kernel: 32 rows/block, 512 thr.
// fp16 hi/lo split-precision MFMA (AhBh + AhBl + AlBh), 3-product = ~fp32.
// State s,v (f32) + operand buffers in LDS (160 KiB). Weights 2-seg split
// [col][hi K | lo K] f16 in ws, read global->VGPR (L2-resident).
// R4 fixes vs R3: no dynamically-indexed register arrays (zero spills),
// GEMMv as one M'=96 GEMM in 2 K-half passes, g kept in regs (C-layout),
// full-unrolled K-loops for compiler software-pipelining of B-loads.
// ---------------------------------------------------------------------------

typedef _Float16 half8 __attribute__((ext_vector_type(8)));
typedef float floatx4 __attribute__((ext_vector_type(4)));

#define NTHR 512

static inline int cdiv_h(int a, int b){ return (a + b - 1) / b; }

__device__ __forceinline__ void split2(float v, _Float16* hi, _Float16* lo){
  _Float16 h = (_Float16)v; *hi = h; *lo = (_Float16)(v - (float)h);
}
__device__ __forceinline__ float red16(float x){
  x += __shfl_xor(x, 1, 64); x += __shfl_xor(x, 2, 64);
  x += __shfl_xor(x, 4, 64); x += __shfl_xor(x, 8, 64);
  return x;
}
// xor-swizzled LDS indexers (2-way bank aliasing = free, m136)
__device__ __forceinline__ int swzA(int row, int h){   // 768-halves rows
  return row*768 + (((h>>3) ^ (row&7))<<3) + (h&7);
}
__device__ __forceinline__ int swzV(int r4, int h){    // 256-halves rows
  return r4*256 + (((h>>3) ^ (r4&7))<<3) + (h&7);
}

// ---------------------------- weight prep ----------------------------------
// 2-seg split: o[col*2K + k] = hi, o[col*2K + K + k] = lo. Scales folded.
// Layer base offsets (halves): W1' 0 (384x768), W2' 294912 (640x768),
// W0' 786432 (128x768), WV' 884736 (128x512); layer stride 950272.
__global__ __launch_bounds__(256) void prep_all2(const float* __restrict__ w1,
                                                 const float* __restrict__ w2,
                                                 const float* __restrict__ w0,
                                                 const float* __restrict__ wv,
                                                 _Float16* __restrict__ W){
  int idx = blockIdx.x*256 + threadIdx.x;
  const int P = 475136;
  if (idx >= 2*P) return;
  int l = (idx >= P) ? 1 : 0;
  int t = idx - l*P;
  const float RS384 = 0.051031036307982884f;    // 1/sqrt(384)
  _Float16* base = W + (size_t)l*950272;
  const float* w; int K, ldw, col, k; float scale; _Float16* o;
  if (t < 147456){ col = t/384; k = t - col*384;
    w = w1 + (size_t)l*147456; K=384; ldw=384; scale=RS384; o = base; }
  else if (t < 393216){ int u = t-147456; col = u/384; k = u - col*384;
    w = w2 + (size_t)l*294912; K=384; ldw=768; scale=RS384; o = base + 294912; }
  else if (t < 442368){ int u = t-393216; col = u/384; k = u - col*384;
    w = w0 + (size_t)l*49152; K=384; ldw=128; scale=RS384; o = base + 786432; }
  else { int u = t-442368; col = u/256; k = u - col*256;
    w = wv + (size_t)l*32768; K=256; ldw=128; scale=0.0625f; o = base + 884736; }
  float v = w[(size_t)k*ldw + col] * scale;
  _Float16 hi = (_Float16)v;
  size_t b = (size_t)col*2*K + k;
  o[b]     = hi;
  o[b + K] = (_Float16)(v - (float)hi);
}

// ------------------- K-loop cores (A in LDS, B global->VGPR) ---------------
// 768-wide A rows (K=384 split pair), B layout [col][hi 384 | lo 384].
template<int MT, int NT>
__device__ __forceinline__ void gcore768(const _Float16* sA768, int row0,
                                         const _Float16* __restrict__ B,
                                         int colbase, floatx4 (&acc)[MT][NT],
                                         int r, int kg){
  const _Float16* bp = B + (colbase + r)*768 + kg*8;
  #pragma unroll
  for (int cc = 0; cc < 12; ++cc){
    half8 bh[NT], bl[NT];
    #pragma unroll
    for (int nt = 0; nt < NT; ++nt){
      bh[nt] = *(const half8*)(bp + nt*16*768 + cc*32);
      bl[nt] = *(const half8*)(bp + nt*16*768 + 384 + cc*32);
    }
    #pragma unroll
    for (int mt = 0; mt < MT; ++mt){
      const int row = row0 + mt*16 + r;
      const int rx = row & 7;
      half8 ah = *(const half8*)(sA768 + row*768 + (((cc*4+kg) ^ rx)<<3));
      half8 al = *(const half8*)(sA768 + row*768 + (((48+cc*4+kg) ^ rx)<<3));
      #pragma unroll
      for (int nt = 0; nt < NT; ++nt){
        acc[mt][nt] = __builtin_amdgcn_mfma_f32_16x16x32_f16(ah, bh[nt], acc[mt][nt], 0, 0, 0);
        acc[mt][nt] = __builtin_amdgcn_mfma_f32_16x16x32_f16(ah, bl[nt], acc[mt][nt], 0, 0, 0);
        acc[mt][nt] = __builtin_amdgcn_mfma_f32_16x16x32_f16(al, bh[nt], acc[mt][nt], 0, 0, 0);
      }
    }
  }
}

// GEMMv core: A4 in sB (96 rows x [hi 128 | lo 128]), B = WV' [c][hi 256|lo 256].
// PASS selects K-half (mm-window), acc accumulates across both passes.
template<int PASS>
__device__ __forceinline__ void gvcore(const _Float16* sB256,
                                       const _Float16* __restrict__ WV,
                                       int colbase, floatx4 (&acc)[6],
                                       int r, int kg){
  const _Float16* bp = WV + (colbase + r)*512 + PASS*128 + kg*8;
  #pragma unroll
  for (int cc = 0; cc < 4; ++cc){
    half8 bh = *(const half8*)(bp + cc*32);
    half8 bl = *(const half8*)(bp + 256 + cc*32);
    #pragma unroll
    for (int rp = 0; rp < 6; ++rp){
      const int r4 = rp*16 + r;
      const int rx = r4 & 7;
      half8 ah = *(const half8*)(sB256 + r4*256 + (((cc*4+kg) ^ rx)<<3));
      half8 al = *(const half8*)(sB256 + r4*256 + (((16+cc*4+kg) ^ rx)<<3));
      acc[rp] = __builtin_amdgcn_mfma_f32_16x16x32_f16(ah, bh, acc[rp], 0, 0, 0);
      acc[rp] = __builtin_amdgcn_mfma_f32_16x16x32_f16(ah, bl, acc[rp], 0, 0, 0);
      acc[rp] = __builtin_amdgcn_mfma_f32_16x16x32_f16(al, bh, acc[rp], 0, 0, 0);
    }
  }
}

// ---------------------------- fused kernel ---------------------------------
__global__ __launch_bounds__(NTHR, 2) void fused(const float* __restrict__ x,
                                                 const _Float16* __restrict__ W,
                                                 const float* __restrict__ g0,
                                                 const float* __restrict__ g1,
                                                 float* __restrict__ out){
  extern __shared__ char lds[];
  float*    sS = (float*)lds;                 // 32x128 f32, 16 KB
  float*    sV = (float*)(lds + 16384);       // 32x[d*128+ch] f32, 48 KB
  _Float16* sA = (_Float16*)(lds + 65536);    // 32x768 h (swz), 48 KB
  _Float16* sB = (_Float16*)(lds + 114688);   // 32x768 h / A4 96x256 h, 48 KB
  float* OVf = (float*)sA;                    // 96x128 f32 = 48 KB (post-GEMMs)
  float* OSf = (float*)sB;                    // 32x128 f32 = 16 KB

  const int tid  = threadIdx.x;
  const int wave = tid >> 6, lane = tid & 63;
  const int r = lane & 15, kg = lane >> 4;
  const int row16 = tid >> 4, j16 = tid & 15;   // owner pattern: 16 thr/row
  const int row0g = blockIdx.x * 32;

  // P0: load 32 rows of x -> sS, sV
  #pragma unroll
  for (int it = 0; it < 32; ++it){
    int flat = it*NTHR + tid;
    int n = flat >> 9, j = flat & 511;
    float val = x[(size_t)(row0g + n)*512 + j];
    if (j < 128) sS[n*128 + j] = val;
    else { int jj = j - 128; int ch = jj/3; int d = jj - ch*3;
           sV[n*384 + d*128 + ch] = val; }
  }
  __syncthreads();

  // P1: layer-0 sc' = [s, s^2, |v|^2/sqrt3] split -> sA
  #pragma unroll
  for (int q = 0; q < 24; ++q){
    int c = j16 + q*16;
    float val;
    if (c < 128) val = sS[row16*128 + c];
    else if (c < 256){ float s = sS[row16*128 + c - 128]; val = s*s; }
    else { int ch = c - 256;
      float a = sV[row16*384 + ch], b = sV[row16*384 + 128 + ch],
            d2 = sV[row16*384 + 256 + ch];
      val = (a*a + b*b + d2*d2) * 0.5773502691896258f; }
    split2(val, &sA[swzA(row16, c)], &sA[swzA(row16, 384 + c)]);
  }
  __syncthreads();                              // B1

  for (int l = 0; l < 2; ++l){
    const _Float16* Wl  = W + l*950272;
    const _Float16* W1p = Wl;
    const _Float16* W2p = Wl + 294912;
    const _Float16* W0p = Wl + 786432;
    const _Float16* WVp = Wl + 884736;

    // ---- G1: h = silu(sc' @ w1'), epilogue split -> sB ----
    {
      floatx4 a1[2][3];
      #pragma unroll
      for (int i = 0; i < 2; ++i)
        #pragma unroll
        for (int j = 0; j < 3; ++j) a1[i][j] = (floatx4){0.f,0.f,0.f,0.f};
      gcore768<2,3>(sA, 0, W1p, wave*48, a1, r, kg);
      #pragma unroll
      for (int mt = 0; mt < 2; ++mt)
        #pragma unroll
        for (int nt = 0; nt < 3; ++nt)
          #pragma unroll
          for (int i = 0; i < 4; ++i){
            int row = mt*16 + kg*4 + i;
            int col = wave*48 + nt*16 + r;
            float v = a1[mt][nt][i];
            float h = v / (1.0f + __expf(-v));
            split2(h, &sB[swzA(row, col)], &sB[swzA(row, 384 + col)]);
          }
    }
    __syncthreads();                            // B2

    // ---- G2: g = h @ w2' (g stays in regs) ----
    floatx4 accg[2][5];
    #pragma unroll
    for (int i = 0; i < 2; ++i)
      #pragma unroll
      for (int j = 0; j < 5; ++j) accg[i][j] = (floatx4){0.f,0.f,0.f,0.f};
    gcore768<2,5>(sB, 0, W2p, wave*80, accg, r, kg);

    // gating epilogue: sc-part in place on sA (bijection -> no races)
    #pragma unroll
    for (int mt = 0; mt < 2; ++mt)
      #pragma unroll
      for (int nt = 0; nt < 5; ++nt){
        int col = wave*80 + nt*16 + r;
        if (col < 384){
          #pragma unroll
          for (int i = 0; i < 4; ++i){
            int row = mt*16 + kg*4 + i;
            int ih = swzA(row, col), il = swzA(row, 384 + col);
            float sc = (float)sA[ih] + (float)sA[il];
            split2(sc * accg[mt][nt][i], &sA[ih], &sA[il]);
          }
        }
      }
    __syncthreads();                            // B3

    // ---- A4 pass-0 build (g cols 384..511 -> vec = v) ----
    #pragma unroll
    for (int mt = 0; mt < 2; ++mt)
      #pragma unroll
      for (int nt = 0; nt < 5; ++nt){
        int col = wave*80 + nt*16 + r;
        if (col >= 384 && col < 512){
          int ch = col - 384;
          #pragma unroll
          for (int i = 0; i < 4; ++i){
            int row = mt*16 + kg*4 + i;
            float g = accg[mt][nt][i];
            #pragma unroll
            for (int d = 0; d < 3; ++d){
              int r4 = d*32 + row;
              float val = sV[row*384 + d*128 + ch] * g;
              split2(val, &sB[swzV(r4, ch)], &sB[swzV(r4, 128 + ch)]);
            }
          }
        }
      }

    // ---- G3: OS = gated sc' @ w0' ----
    floatx4 acc0[1][2];
    acc0[0][0] = (floatx4){0.f,0.f,0.f,0.f};
    acc0[0][1] = (floatx4){0.f,0.f,0.f,0.f};
    gcore768<1,2>(sA, (wave&1)*16, W0p, (wave>>1)*32, acc0, r, kg);
    __syncthreads();                            // B4

    // ---- GEMMv pass 0 ----
    floatx4 accv[6];
    #pragma unroll
    for (int i = 0; i < 6; ++i) accv[i] = (floatx4){0.f,0.f,0.f,0.f};
    gvcore<0>(sB, WVp, wave*16, accv, r, kg);
    __syncthreads();                            // B5

    // ---- A4 pass-1 build (g cols 512..639 -> vec = sqrt2*s*v) ----
    #pragma unroll
    for (int mt = 0; mt < 2; ++mt)
      #pragma unroll
      for (int nt = 0; nt < 5; ++nt){
        int col = wave*80 + nt*16 + r;
        if (col >= 512){
          int ch = col - 512;
          #pragma unroll
          for (int i = 0; i < 4; ++i){
            int row = mt*16 + kg*4 + i;
            float gs = 1.4142135623730951f * sS[row*128 + ch] * accg[mt][nt][i];
            #pragma unroll
            for (int d = 0; d < 3; ++d){
              int r4 = d*32 + row;
              float val = sV[row*384 + d*128 + ch] * gs;
              split2(val, &sB[swzV(r4, ch)], &sB[swzV(r4, 128 + ch)]);
            }
          }
        }
      }
    __syncthreads();                            // B6

    // ---- GEMMv pass 1 (accumulates into accv) ----
    gvcore<1>(sB, WVp, wave*16, accv, r, kg);
    __syncthreads();                            // B7

    // ---- dump OS -> sB(f32), OV -> sA(f32) ----
    #pragma unroll
    for (int ct = 0; ct < 2; ++ct)
      #pragma unroll
      for (int i = 0; i < 4; ++i){
        int row = (wave&1)*16 + kg*4 + i;
        int col = (wave>>1)*32 + ct*16 + r;
        OSf[row*128 + col] = acc0[0][ct][i];
      }
    #pragma unroll
    for (int rp = 0; rp < 6; ++rp)
      #pragma unroll
      for (int i = 0; i < 4; ++i){
        int r4 = rp*16 + kg*4 + i;
        int col = wave*16 + r;
        OVf[r4*128 + col] = accv[rp][i];
      }
    __syncthreads();                            // B8

    // ---- P7a: residual (reads) ----
    float sacc[8], vacc[24];
    float ssum = 0.f;
    #pragma unroll
    for (int q = 0; q < 8; ++q){
      int c = j16 + q*16;
      sacc[q] = sS[row16*128 + c] + OSf[row16*128 + c];
      ssum += sacc[q];
    }
    #pragma unroll
    for (int q = 0; q < 24; ++q){
      int e = j16 + q*16;
      int d = e >> 7, ch = e & 127;
      vacc[q] = sV[row16*384 + e] + OVf[(d*32 + row16)*128 + ch];
    }
    __syncthreads();                            // B9

    // ---- P7b: (l=0) eq-LN -> state + next sc' | (l=1) final output ----
    if (l == 0){
      float mu = red16(ssum) * (1.0f/128.0f);
      float var = 0.f;
      #pragma unroll
      for (int q = 0; q < 8; ++q){ float d = sacc[q] - mu; var += d*d; }
      var = red16(var) * (1.0f/128.0f);
      float sd = sqrtf(var + 1e-6f);
      float v2 = 0.f;
      #pragma unroll
      for (int q = 0; q < 24; ++q) v2 += vacc[q]*vacc[q];
      float rms = sqrtf(red16(v2) * (1.0f/384.0f) + 1e-6f);
      float ns[8], nv[24];
      #pragma unroll
      for (int q = 0; q < 8; ++q){
        int c = j16 + q*16;
        ns[q] = (sacc[q] - mu) / sd * g0[c];
        sS[row16*128 + c] = ns[q];
      }
      #pragma unroll
      for (int q = 0; q < 24; ++q){
        int e = j16 + q*16;
        nv[q] = vacc[q] / rms * g1[e & 127];
        sV[row16*384 + e] = nv[q];
      }
      // next layer's sc' into sA
      #pragma unroll
      for (int q = 0; q < 24; ++q){
        int c = j16 + q*16;
        float val;
        if (c < 128) val = ns[q];
        else if (c < 256) val = ns[q-8]*ns[q-8];
        else {
          int t = q - 16;
          val = (nv[t]*nv[t] + nv[t+8]*nv[t+8] + nv[t+16]*nv[t+16])
                * 0.5773502691896258f;
        }
        split2(val, &sA[swzA(row16, c)], &sA[swzA(row16, 384 + c)]);
      }
    } else {
      size_t ob = (size_t)(row0g + row16)*512;
      #pragma unroll
      for (int q = 0; q < 8; ++q){
        int c = j16 + q*16;
        out[ob + c] = sacc[q];
      }
      #pragma unroll
      for (int q = 0; q < 24; ++q){
        int e = j16 + q*16;
        int d = e >> 7, ch = e & 127;
        out[ob + 128 + ch*3 + d] = vacc[q];
      }
    }
    __syncthreads();                            // B10 (next layer's B1)
  }
}

// ---------------------------- host launcher --------------------------------

extern "C" void kernel_launch(void* const* d_in, const int* in_sizes, int n_in,
                              void* d_out, int out_size, void* d_ws, size_t ws_size,
                              hipStream_t stream){
  const float* x  = (const float*)d_in[0];
  const float* w1 = (const float*)d_in[1];
  const float* w2 = (const float*)d_in[2];
  const float* w0 = (const float*)d_in[3];
  const float* wv = (const float*)d_in[4];
  const float* g0 = (const float*)d_in[5];
  const float* g1 = (const float*)d_in[6];
  float* out = (float*)d_out;
  const int N = in_sizes[0] / 512;                 // 16384

  _Float16* W = (_Float16*)d_ws;                   // 2 x 950272 halves = 3.8 MB

  prep_all2<<<cdiv_h(950272,256),256,0,stream>>>(w1, w2, w0, wv, W);
  fused<<<N/32, NTHR, 163840, stream>>>(x, W, g0, g1, out);
}

// Round 5
// 510.249 us; speedup vs baseline: 1.2217x; 1.1579x over previous
//
#include <hip/hip_runtime.h>

// ---------------------------------------------------------------------------
// SelfInteraction, fully fused persistent kernel: 32 rows/block, 512 thr.
// fp16 hi/lo split-precision MFMA (AhBh + AhBl + AlBh = ~fp32).
// R5 vs R4: (1) waves_per_eu(2,2) -> 256-VGPR budget (LDS caps at 1 blk/CU
// anyway) so nothing spills; (2) GEMMv split by PRECISION TERM not K-half:
// A4_hi (f16, full K=256) in sB, A4_lo in sA (after G3 frees it) -- accg
// dies at A4_lo build instead of living across two GEMM cores;
// (3) unroll_count(2) on K-loops to stop B-load over-hoisting.
// ---------------------------------------------------------------------------

typedef _Float16 half8 __attribute__((ext_vector_type(8)));
typedef float floatx4 __attribute__((ext_vector_type(4)));

#define NTHR 512

static inline int cdiv_h(int a, int b){ return (a + b - 1) / b; }

__device__ __forceinline__ void split2(float v, _Float16* hi, _Float16* lo){
  _Float16 h = (_Float16)v; *hi = h; *lo = (_Float16)(v - (float)h);
}
__device__ __forceinline__ float red16(float x){
  x += __shfl_xor(x, 1, 64); x += __shfl_xor(x, 2, 64);
  x += __shfl_xor(x, 4, 64); x += __shfl_xor(x, 8, 64);
  return x;
}
// xor-swizzled LDS indexers (2-way bank aliasing = free, m136)
__device__ __forceinline__ int swzA(int row, int h){   // 768-halves rows
  return row*768 + (((h>>3) ^ (row&7))<<3) + (h&7);
}
__device__ __forceinline__ int swz256(int r4, int h){  // 256-halves rows
  return r4*256 + (((h>>3) ^ (r4&7))<<3) + (h&7);
}

// ---------------------------- weight prep ----------------------------------
// 2-seg split: o[col*2K + k] = hi, o[col*2K + K + k] = lo. Scales folded.
// Layer base (halves): W1' 0 (384x768), W2' 294912 (640x768),
// W0' 786432 (128x768), WV' 884736 (128x512); layer stride 950272.
__global__ __launch_bounds__(256) void prep_all2(const float* __restrict__ w1,
                                                 const float* __restrict__ w2,
                                                 const float* __restrict__ w0,
                                                 const float* __restrict__ wv,
                                                 _Float16* __restrict__ W){
  int idx = blockIdx.x*256 + threadIdx.x;
  const int P = 475136;
  if (idx >= 2*P) return;
  int l = (idx >= P) ? 1 : 0;
  int t = idx - l*P;
  const float RS384 = 0.051031036307982884f;    // 1/sqrt(384)
  _Float16* base = W + (size_t)l*950272;
  const float* w; int K, ldw, col, k; float scale; _Float16* o;
  if (t < 147456){ col = t/384; k = t - col*384;
    w = w1 + (size_t)l*147456; K=384; ldw=384; scale=RS384; o = base; }
  else if (t < 393216){ int u = t-147456; col = u/384; k = u - col*384;
    w = w2 + (size_t)l*294912; K=384; ldw=768; scale=RS384; o = base + 294912; }
  else if (t < 442368){ int u = t-393216; col = u/384; k = u - col*384;
    w = w0 + (size_t)l*49152; K=384; ldw=128; scale=RS384; o = base + 786432; }
  else { int u = t-442368; col = u/256; k = u - col*256;
    w = wv + (size_t)l*32768; K=256; ldw=128; scale=0.0625f; o = base + 884736; }
  float v = w[(size_t)k*ldw + col] * scale;
  _Float16 hi = (_Float16)v;
  size_t b = (size_t)col*2*K + k;
  o[b]     = hi;
  o[b + K] = (_Float16)(v - (float)hi);
}

// ------------------- K-loop cores (A in LDS, B global->VGPR) ---------------
// K=384 split-pair A rows (768 halves wide), B layout [col][hi 384 | lo 384].
template<int MT, int NT>
__device__ __forceinline__ void gcore768(const _Float16* sAp, int row0,
                                         const _Float16* __restrict__ B,
                                         int colbase, floatx4 (&acc)[MT][NT],
                                         int r, int kg){
  const _Float16* bp = B + (colbase + r)*768 + kg*8;
  #pragma clang loop unroll_count(2)
  for (int cc = 0; cc < 12; ++cc){
    half8 bh[NT], bl[NT];
    #pragma unroll
    for (int nt = 0; nt < NT; ++nt){
      bh[nt] = *(const half8*)(bp + nt*16*768 + cc*32);
      bl[nt] = *(const half8*)(bp + nt*16*768 + 384 + cc*32);
    }
    #pragma unroll
    for (int mt = 0; mt < MT; ++mt){
      const int row = row0 + mt*16 + r;
      const int rx = row & 7;
      half8 ah = *(const half8*)(sAp + row*768 + (((cc*4+kg) ^ rx)<<3));
      half8 al = *(const half8*)(sAp + row*768 + (((48+cc*4+kg) ^ rx)<<3));
      #pragma unroll
      for (int nt = 0; nt < NT; ++nt){
        acc[mt][nt] = __builtin_amdgcn_mfma_f32_16x16x32_f16(ah, bh[nt], acc[mt][nt], 0, 0, 0);
        acc[mt][nt] = __builtin_amdgcn_mfma_f32_16x16x32_f16(ah, bl[nt], acc[mt][nt], 0, 0, 0);
        acc[mt][nt] = __builtin_amdgcn_mfma_f32_16x16x32_f16(al, bh[nt], acc[mt][nt], 0, 0, 0);
      }
    }
  }
}

// GEMMv core: A4 (96 rows x 256 halves, plain f16, full K=256) in LDS,
// B = WV' [col][hi 256 | lo 256]. NPROD=2: a*Bh + a*Bl; NPROD=1: a*Bh.
template<int NPROD>
__device__ __forceinline__ void gvcore(const _Float16* sBuf,
                                       const _Float16* __restrict__ WV,
                                       int colbase, floatx4 (&acc)[6],
                                       int r, int kg){
  const _Float16* bp = WV + (colbase + r)*512 + kg*8;
  #pragma clang loop unroll_count(2)
  for (int cc = 0; cc < 8; ++cc){
    half8 bh = *(const half8*)(bp + cc*32);
    half8 bl;
    if (NPROD == 2) bl = *(const half8*)(bp + 256 + cc*32);
    #pragma unroll
    for (int rp = 0; rp < 6; ++rp){
      const int r4 = rp*16 + r;
      const int rx = r4 & 7;
      half8 a = *(const half8*)(sBuf + r4*256 + (((cc*4+kg) ^ rx)<<3));
      acc[rp] = __builtin_amdgcn_mfma_f32_16x16x32_f16(a, bh, acc[rp], 0, 0, 0);
      if (NPROD == 2)
        acc[rp] = __builtin_amdgcn_mfma_f32_16x16x32_f16(a, bl, acc[rp], 0, 0, 0);
    }
  }
}

// ---------------------------- fused kernel ---------------------------------
__global__ __launch_bounds__(NTHR)
__attribute__((amdgpu_waves_per_eu(2, 2)))
void fused(const float* __restrict__ x,
           const _Float16* __restrict__ W,
           const float* __restrict__ g0,
           const float* __restrict__ g1,
           float* __restrict__ out){
  extern __shared__ char lds[];
  float*    sS = (float*)lds;                 // 32x128 f32, 16 KB
  float*    sV = (float*)(lds + 16384);       // 32x[d*128+ch] f32, 48 KB
  _Float16* sA = (_Float16*)(lds + 65536);    // sc' 32x768 / A4_lo 96x256, 48 KB
  _Float16* sB = (_Float16*)(lds + 114688);   // h' 32x768 / A4_hi 96x256, 48 KB
  float* OVf = (float*)sA;                    // 96x128 f32 (post-GEMMs)
  float* OSf = (float*)sB;                    // 32x128 f32

  const int tid  = threadIdx.x;
  const int wave = tid >> 6, lane = tid & 63;
  const int r = lane & 15, kg = lane >> 4;
  const int row16 = tid >> 4, j16 = tid & 15;
  const int row0g = blockIdx.x * 32;

  // P0: load 32 rows of x -> sS, sV (v d-major)
  #pragma unroll
  for (int it = 0; it < 32; ++it){
    int flat = it*NTHR + tid;
    int n = flat >> 9, j = flat & 511;
    float val = x[(size_t)(row0g + n)*512 + j];
    if (j < 128) sS[n*128 + j] = val;
    else { int jj = j - 128; int ch = jj/3; int d = jj - ch*3;
           sV[n*384 + d*128 + ch] = val; }
  }
  __syncthreads();

  // P1: layer-0 sc' -> sA
  #pragma unroll
  for (int q = 0; q < 24; ++q){
    int c = j16 + q*16;
    float val;
    if (c < 128) val = sS[row16*128 + c];
    else if (c < 256){ float s = sS[row16*128 + c - 128]; val = s*s; }
    else { int ch = c - 256;
      float a = sV[row16*384 + ch], b = sV[row16*384 + 128 + ch],
            d2 = sV[row16*384 + 256 + ch];
      val = (a*a + b*b + d2*d2) * 0.5773502691896258f; }
    split2(val, &sA[swzA(row16, c)], &sA[swzA(row16, 384 + c)]);
  }
  __syncthreads();

  for (int l = 0; l < 2; ++l){
    const _Float16* Wl  = W + l*950272;
    const _Float16* W1p = Wl;
    const _Float16* W2p = Wl + 294912;
    const _Float16* W0p = Wl + 786432;
    const _Float16* WVp = Wl + 884736;

    // ---- G1: h = silu(sc' @ w1') -> sB (split) ----
    {
      floatx4 a1[2][3];
      #pragma unroll
      for (int i = 0; i < 2; ++i)
        #pragma unroll
        for (int j = 0; j < 3; ++j) a1[i][j] = (floatx4){0.f,0.f,0.f,0.f};
      gcore768<2,3>(sA, 0, W1p, wave*48, a1, r, kg);
      #pragma unroll
      for (int mt = 0; mt < 2; ++mt)
        #pragma unroll
        for (int nt = 0; nt < 3; ++nt)
          #pragma unroll
          for (int i = 0; i < 4; ++i){
            int row = mt*16 + kg*4 + i;
            int col = wave*48 + nt*16 + r;
            float v = a1[mt][nt][i];
            float h = v / (1.0f + __expf(-v));
            split2(h, &sB[swzA(row, col)], &sB[swzA(row, 384 + col)]);
          }
    }
    __syncthreads();                            // B2

    // ---- G2: g = h @ w2' (in regs); gate sc' in place on sA ----
    floatx4 accg[2][5];
    #pragma unroll
    for (int i = 0; i < 2; ++i)
      #pragma unroll
      for (int j = 0; j < 5; ++j) accg[i][j] = (floatx4){0.f,0.f,0.f,0.f};
    gcore768<2,5>(sB, 0, W2p, wave*80, accg, r, kg);

    #pragma unroll
    for (int mt = 0; mt < 2; ++mt)
      #pragma unroll
      for (int nt = 0; nt < 5; ++nt){
        int col = wave*80 + nt*16 + r;
        if (col < 384){
          #pragma unroll
          for (int i = 0; i < 4; ++i){
            int row = mt*16 + kg*4 + i;
            int ih = swzA(row, col), il = swzA(row, 384 + col);
            float sc = (float)sA[ih] + (float)sA[il];
            split2(sc * accg[mt][nt][i], &sA[ih], &sA[il]);
          }
        }
      }
    __syncthreads();                            // B3 (sB free)

    // ---- phase 3: A4_hi -> sB (f16, full K) ; G3 (reads gated sA) ----
    #pragma unroll
    for (int mt = 0; mt < 2; ++mt)
      #pragma unroll
      for (int nt = 0; nt < 5; ++nt){
        int col = wave*80 + nt*16 + r;
        if (col >= 384){
          int mm = col - 384, ch = mm & 127;
          #pragma unroll
          for (int i = 0; i < 4; ++i){
            int row = mt*16 + kg*4 + i;
            float g = accg[mt][nt][i];
            float gm = (mm >= 128) ? 1.4142135623730951f * sS[row*128 + ch] * g : g;
            #pragma unroll
            for (int d = 0; d < 3; ++d){
              float val = sV[row*384 + d*128 + ch] * gm;
              sB[swz256(d*32 + row, mm)] = (_Float16)val;
            }
          }
        }
      }

    floatx4 acc0[1][2];
    acc0[0][0] = (floatx4){0.f,0.f,0.f,0.f};
    acc0[0][1] = (floatx4){0.f,0.f,0.f,0.f};
    gcore768<1,2>(sA, (wave&1)*16, W0p, (wave>>1)*32, acc0, r, kg);
    __syncthreads();                            // B4 (sA free)

    // ---- phase 4: A4_lo -> sA (accg dies here) ; GEMMv-A on sB ----
    #pragma unroll
    for (int mt = 0; mt < 2; ++mt)
      #pragma unroll
      for (int nt = 0; nt < 5; ++nt){
        int col = wave*80 + nt*16 + r;
        if (col >= 384){
          int mm = col - 384, ch = mm & 127;
          #pragma unroll
          for (int i = 0; i < 4; ++i){
            int row = mt*16 + kg*4 + i;
            float g = accg[mt][nt][i];
            float gm = (mm >= 128) ? 1.4142135623730951f * sS[row*128 + ch] * g : g;
            #pragma unroll
            for (int d = 0; d < 3; ++d){
              float val = sV[row*384 + d*128 + ch] * gm;
              sA[swz256(d*32 + row, mm)] = (_Float16)(val - (float)(_Float16)val);
            }
          }
        }
      }

    floatx4 accv[6];
    #pragma unroll
    for (int i = 0; i < 6; ++i) accv[i] = (floatx4){0.f,0.f,0.f,0.f};
    gvcore<2>(sB, WVp, wave*16, accv, r, kg);   // Ah*Bh + Ah*Bl
    __syncthreads();                            // B5

    // ---- phase 5: GEMMv-B on sA (Al*Bh) ----
    gvcore<1>(sA, WVp, wave*16, accv, r, kg);
    __syncthreads();                            // B6

    // ---- dump OS -> sB(f32), OV -> sA(f32) ----
    #pragma unroll
    for (int ct = 0; ct < 2; ++ct)
      #pragma unroll
      for (int i = 0; i < 4; ++i){
        int row = (wave&1)*16 + kg*4 + i;
        int col = (wave>>1)*32 + ct*16 + r;
        OSf[row*128 + col] = acc0[0][ct][i];
      }
    #pragma unroll
    for (int rp = 0; rp < 6; ++rp)
      #pragma unroll
      for (int i = 0; i < 4; ++i){
        int r4 = rp*16 + kg*4 + i;
        int col = wave*16 + r;
        OVf[r4*128 + col] = accv[rp][i];
      }
    __syncthreads();                            // B7

    // ---- P7a: residual reads ----
    float sacc[8], vacc[24];
    float ssum = 0.f;
    #pragma unroll
    for (int q = 0; q < 8; ++q){
      int c = j16 + q*16;
      sacc[q] = sS[row16*128 + c] + OSf[row16*128 + c];
      ssum += sacc[q];
    }
    #pragma unroll
    for (int q = 0; q < 24; ++q){
      int e = j16 + q*16;
      int d = e >> 7, ch = e & 127;
      vacc[q] = sV[row16*384 + e] + OVf[(d*32 + row16)*128 + ch];
    }
    __syncthreads();                            // B8

    // ---- P7b: (l=0) eq-LN + next sc' | (l=1) final output ----
    if (l == 0){
      float mu = red16(ssum) * (1.0f/128.0f);
      float var = 0.f;
      #pragma unroll
      for (int q = 0; q < 8; ++q){ float d = sacc[q] - mu; var += d*d; }
      var = red16(var) * (1.0f/128.0f);
      float sd = sqrtf(var + 1e-6f);
      float v2 = 0.f;
      #pragma unroll
      for (int q = 0; q < 24; ++q) v2 += vacc[q]*vacc[q];
      float rms = sqrtf(red16(v2) * (1.0f/384.0f) + 1e-6f);
      float ns[8], nv[24];
      #pragma unroll
      for (int q = 0; q < 8; ++q){
        int c = j16 + q*16;
        ns[q] = (sacc[q] - mu) / sd * g0[c];
        sS[row16*128 + c] = ns[q];
      }
      #pragma unroll
      for (int q = 0; q < 24; ++q){
        int e = j16 + q*16;
        nv[q] = vacc[q] / rms * g1[e & 127];
        sV[row16*384 + e] = nv[q];
      }
      #pragma unroll
      for (int q = 0; q < 24; ++q){
        int c = j16 + q*16;
        float val;
        if (c < 128) val = ns[q];
        else if (c < 256) val = ns[q-8]*ns[q-8];
        else {
          int t = q - 16;
          val = (nv[t]*nv[t] + nv[t+8]*nv[t+8] + nv[t+16]*nv[t+16])
                * 0.5773502691896258f;
        }
        split2(val, &sA[swzA(row16, c)], &sA[swzA(row16, 384 + c)]);
      }
    } else {
      size_t ob = (size_t)(row0g + row16)*512;
      #pragma unroll
      for (int q = 0; q < 8; ++q){
        int c = j16 + q*16;
        out[ob + c] = sacc[q];
      }
      #pragma unroll
      for (int q = 0; q < 24; ++q){
        int e = j16 + q*16;
        int d = e >> 7, ch = e & 127;
        out[ob + 128 + ch*3 + d] = vacc[q];
      }
    }
    __syncthreads();                            // B9
  }
}

// ---------------------------- host launcher --------------------------------

extern "C" void kernel_launch(void* const* d_in, const int* in_sizes, int n_in,
                              void* d_out, int out_size, void* d_ws, size_t ws_size,
                              hipStream_t stream){
  const float* x  = (const float*)d_in[0];
  const float* w1 = (const float*)d_in[1];
  const float* w2 = (const float*)d_in[2];
  const float* w0 = (const float*)d_in[3];
  const float* wv = (const float*)d_in[4];
  const float* g0 = (const float*)d_in[5];
  const float* g1 = (const float*)d_in[6];
  float* out = (float*)d_out;
  const int N = in_sizes[0] / 512;                 // 16384

  _Float16* W = (_Float16*)d_ws;                   // 2 x 950272 halves = 3.8 MB

  prep_all2<<<cdiv_h(950272,256),256,0,stream>>>(w1, w2, w0, wv, W);
  fused<<<N/32, NTHR, 163840, stream>>>(x, W, g0, g1, out);
}

// Round 6
// 500.563 us; speedup vs baseline: 1.2454x; 1.0193x over previous
//
#include <hip/hip_runtime.h>

// ---------------------------------------------------------------------------
// SelfInteraction, fully fused persistent kernel: 32 rows/block, 512 thr.
// fp16 hi/lo split-precision MFMA (AhBh + AhBl + AlBh = ~fp32).
// R6 vs R5: GEMM cores restructured for LOW ARCH-VGPR LIVENESS (<128):
// nt-inner loops load one B hi/lo pair at a time (8 regs in flight) instead
// of all NT pairs (40 regs); cc-loop unrolling disabled. R4/R5's ~130 MB of
// per-iteration scratch spill traffic should vanish.
// ---------------------------------------------------------------------------

typedef _Float16 half8 __attribute__((ext_vector_type(8)));
typedef float floatx4 __attribute__((ext_vector_type(4)));

#define NTHR 512

static inline int cdiv_h(int a, int b){ return (a + b - 1) / b; }

__device__ __forceinline__ void split2(float v, _Float16* hi, _Float16* lo){
  _Float16 h = (_Float16)v; *hi = h; *lo = (_Float16)(v - (float)h);
}
__device__ __forceinline__ float red16(float x){
  x += __shfl_xor(x, 1, 64); x += __shfl_xor(x, 2, 64);
  x += __shfl_xor(x, 4, 64); x += __shfl_xor(x, 8, 64);
  return x;
}
// xor-swizzled LDS indexers (2-way bank aliasing = free, m136)
__device__ __forceinline__ int swzA(int row, int h){   // 768-halves rows
  return row*768 + (((h>>3) ^ (row&7))<<3) + (h&7);
}
__device__ __forceinline__ int swz256(int r4, int h){  // 256-halves rows
  return r4*256 + (((h>>3) ^ (r4&7))<<3) + (h&7);
}

// ---------------------------- weight prep ----------------------------------
// 2-seg split: o[col*2K + k] = hi, o[col*2K + K + k] = lo. Scales folded.
// Layer base (halves): W1' 0 (384x768), W2' 294912 (640x768),
// W0' 786432 (128x768), WV' 884736 (128x512); layer stride 950272.
__global__ __launch_bounds__(256) void prep_all2(const float* __restrict__ w1,
                                                 const float* __restrict__ w2,
                                                 const float* __restrict__ w0,
                                                 const float* __restrict__ wv,
                                                 _Float16* __restrict__ W){
  int idx = blockIdx.x*256 + threadIdx.x;
  const int P = 475136;
  if (idx >= 2*P) return;
  int l = (idx >= P) ? 1 : 0;
  int t = idx - l*P;
  const float RS384 = 0.051031036307982884f;    // 1/sqrt(384)
  _Float16* base = W + (size_t)l*950272;
  const float* w; int K, ldw, col, k; float scale; _Float16* o;
  if (t < 147456){ col = t/384; k = t - col*384;
    w = w1 + (size_t)l*147456; K=384; ldw=384; scale=RS384; o = base; }
  else if (t < 393216){ int u = t-147456; col = u/384; k = u - col*384;
    w = w2 + (size_t)l*294912; K=384; ldw=768; scale=RS384; o = base + 294912; }
  else if (t < 442368){ int u = t-393216; col = u/384; k = u - col*384;
    w = w0 + (size_t)l*49152; K=384; ldw=128; scale=RS384; o = base + 786432; }
  else { int u = t-442368; col = u/256; k = u - col*256;
    w = wv + (size_t)l*32768; K=256; ldw=128; scale=0.0625f; o = base + 884736; }
  float v = w[(size_t)k*ldw + col] * scale;
  _Float16 hi = (_Float16)v;
  size_t b = (size_t)col*2*K + k;
  o[b]     = hi;
  o[b + K] = (_Float16)(v - (float)hi);
}

// ------------------- K-loop cores (A in LDS, B global->VGPR) ---------------
// K=384 split-pair A rows (768 halves wide), B layout [col][hi 384 | lo 384].
// nt-INNER structure: one bh/bl pair in flight at a time -> low liveness.
template<int MT, int NT>
__device__ __forceinline__ void gcore768(const _Float16* sAp, int row0,
                                         const _Float16* __restrict__ B,
                                         int colbase, floatx4 (&acc)[MT][NT],
                                         int r, int kg){
  const _Float16* bp = B + (colbase + r)*768 + kg*8;
  #pragma clang loop unroll(disable)
  for (int cc = 0; cc < 12; ++cc){
    half8 ah[MT], al[MT];
    #pragma unroll
    for (int mt = 0; mt < MT; ++mt){
      const int row = row0 + mt*16 + r;
      const int rx = row & 7;
      ah[mt] = *(const half8*)(sAp + row*768 + (((cc*4+kg) ^ rx)<<3));
      al[mt] = *(const half8*)(sAp + row*768 + (((48+cc*4+kg) ^ rx)<<3));
    }
    #pragma unroll
    for (int nt = 0; nt < NT; ++nt){
      half8 bh = *(const half8*)(bp + nt*16*768 + cc*32);
      half8 bl = *(const half8*)(bp + nt*16*768 + 384 + cc*32);
      #pragma unroll
      for (int mt = 0; mt < MT; ++mt){
        acc[mt][nt] = __builtin_amdgcn_mfma_f32_16x16x32_f16(ah[mt], bh, acc[mt][nt], 0, 0, 0);
        acc[mt][nt] = __builtin_amdgcn_mfma_f32_16x16x32_f16(ah[mt], bl, acc[mt][nt], 0, 0, 0);
        acc[mt][nt] = __builtin_amdgcn_mfma_f32_16x16x32_f16(al[mt], bh, acc[mt][nt], 0, 0, 0);
      }
    }
  }
}

// GEMMv core: A4 (96 rows x 256 halves, plain f16, full K=256) in LDS,
// B = WV' [col][hi 256 | lo 256]. NPROD=2: a*Bh + a*Bl; NPROD=1: a*Bh.
template<int NPROD>
__device__ __forceinline__ void gvcore(const _Float16* sBuf,
                                       const _Float16* __restrict__ WV,
                                       int colbase, floatx4 (&acc)[6],
                                       int r, int kg){
  const _Float16* bp = WV + (colbase + r)*512 + kg*8;
  #pragma clang loop unroll(disable)
  for (int cc = 0; cc < 8; ++cc){
    half8 bh = *(const half8*)(bp + cc*32);
    half8 bl;
    if (NPROD == 2) bl = *(const half8*)(bp + 256 + cc*32);
    #pragma unroll
    for (int rp = 0; rp < 6; ++rp){
      const int r4 = rp*16 + r;
      const int rx = r4 & 7;
      half8 a = *(const half8*)(sBuf + r4*256 + (((cc*4+kg) ^ rx)<<3));
      acc[rp] = __builtin_amdgcn_mfma_f32_16x16x32_f16(a, bh, acc[rp], 0, 0, 0);
      if (NPROD == 2)
        acc[rp] = __builtin_amdgcn_mfma_f32_16x16x32_f16(a, bl, acc[rp], 0, 0, 0);
    }
  }
}

// ---------------------------- fused kernel ---------------------------------
__global__ __launch_bounds__(NTHR)
__attribute__((amdgpu_waves_per_eu(2, 2)))
void fused(const float* __restrict__ x,
           const _Float16* __restrict__ W,
           const float* __restrict__ g0,
           const float* __restrict__ g1,
           float* __restrict__ out){
  extern __shared__ char lds[];
  float*    sS = (float*)lds;                 // 32x128 f32, 16 KB
  float*    sV = (float*)(lds + 16384);       // 32x[d*128+ch] f32, 48 KB
  _Float16* sA = (_Float16*)(lds + 65536);    // sc' 32x768 / A4_lo 96x256, 48 KB
  _Float16* sB = (_Float16*)(lds + 114688);   // h' 32x768 / A4_hi 96x256, 48 KB
  float* OVf = (float*)sA;                    // 96x128 f32 (post-GEMMs)
  float* OSf = (float*)sB;                    // 32x128 f32

  const int tid  = threadIdx.x;
  const int wave = tid >> 6, lane = tid & 63;
  const int r = lane & 15, kg = lane >> 4;
  const int row16 = tid >> 4, j16 = tid & 15;
  const int row0g = blockIdx.x * 32;

  // P0: load 32 rows of x -> sS, sV (v d-major)
  #pragma unroll
  for (int it = 0; it < 32; ++it){
    int flat = it*NTHR + tid;
    int n = flat >> 9, j = flat & 511;
    float val = x[(size_t)(row0g + n)*512 + j];
    if (j < 128) sS[n*128 + j] = val;
    else { int jj = j - 128; int ch = jj/3; int d = jj - ch*3;
           sV[n*384 + d*128 + ch] = val; }
  }
  __syncthreads();

  // P1: layer-0 sc' -> sA
  #pragma unroll
  for (int q = 0; q < 24; ++q){
    int c = j16 + q*16;
    float val;
    if (c < 128) val = sS[row16*128 + c];
    else if (c < 256){ float s = sS[row16*128 + c - 128]; val = s*s; }
    else { int ch = c - 256;
      float a = sV[row16*384 + ch], b = sV[row16*384 + 128 + ch],
            d2 = sV[row16*384 + 256 + ch];
      val = (a*a + b*b + d2*d2) * 0.5773502691896258f; }
    split2(val, &sA[swzA(row16, c)], &sA[swzA(row16, 384 + c)]);
  }
  __syncthreads();

  for (int l = 0; l < 2; ++l){
    const _Float16* Wl  = W + l*950272;
    const _Float16* W1p = Wl;
    const _Float16* W2p = Wl + 294912;
    const _Float16* W0p = Wl + 786432;
    const _Float16* WVp = Wl + 884736;

    // ---- G1: h = silu(sc' @ w1') -> sB (split) ----
    {
      floatx4 a1[2][3];
      #pragma unroll
      for (int i = 0; i < 2; ++i)
        #pragma unroll
        for (int j = 0; j < 3; ++j) a1[i][j] = (floatx4){0.f,0.f,0.f,0.f};
      gcore768<2,3>(sA, 0, W1p, wave*48, a1, r, kg);
      #pragma unroll
      for (int mt = 0; mt < 2; ++mt)
        #pragma unroll
        for (int nt = 0; nt < 3; ++nt)
          #pragma unroll
          for (int i = 0; i < 4; ++i){
            int row = mt*16 + kg*4 + i;
            int col = wave*48 + nt*16 + r;
            float v = a1[mt][nt][i];
            float h = v / (1.0f + __expf(-v));
            split2(h, &sB[swzA(row, col)], &sB[swzA(row, 384 + col)]);
          }
    }
    __syncthreads();                            // B2

    // ---- G2: g = h @ w2' (in regs); gate sc' in place on sA ----
    floatx4 accg[2][5];
    #pragma unroll
    for (int i = 0; i < 2; ++i)
      #pragma unroll
      for (int j = 0; j < 5; ++j) accg[i][j] = (floatx4){0.f,0.f,0.f,0.f};
    gcore768<2,5>(sB, 0, W2p, wave*80, accg, r, kg);

    #pragma unroll
    for (int mt = 0; mt < 2; ++mt)
      #pragma unroll
      for (int nt = 0; nt < 5; ++nt){
        int col = wave*80 + nt*16 + r;
        if (col < 384){
          #pragma unroll
          for (int i = 0; i < 4; ++i){
            int row = mt*16 + kg*4 + i;
            int ih = swzA(row, col), il = swzA(row, 384 + col);
            float sc = (float)sA[ih] + (float)sA[il];
            split2(sc * accg[mt][nt][i], &sA[ih], &sA[il]);
          }
        }
      }
    __syncthreads();                            // B3 (sB free)

    // ---- phase 3: A4_hi -> sB (f16, full K) ; G3 (reads gated sA) ----
    #pragma unroll
    for (int mt = 0; mt < 2; ++mt)
      #pragma unroll
      for (int nt = 0; nt < 5; ++nt){
        int col = wave*80 + nt*16 + r;
        if (col >= 384){
          int mm = col - 384, ch = mm & 127;
          #pragma unroll
          for (int i = 0; i < 4; ++i){
            int row = mt*16 + kg*4 + i;
            float g = accg[mt][nt][i];
            float gm = (mm >= 128) ? 1.4142135623730951f * sS[row*128 + ch] * g : g;
            #pragma unroll
            for (int d = 0; d < 3; ++d){
              float val = sV[row*384 + d*128 + ch] * gm;
              sB[swz256(d*32 + row, mm)] = (_Float16)val;
            }
          }
        }
      }

    floatx4 acc0[1][2];
    acc0[0][0] = (floatx4){0.f,0.f,0.f,0.f};
    acc0[0][1] = (floatx4){0.f,0.f,0.f,0.f};
    gcore768<1,2>(sA, (wave&1)*16, W0p, (wave>>1)*32, acc0, r, kg);
    __syncthreads();                            // B4 (sA free)

    // ---- phase 4: A4_lo -> sA (accg dies here) ; GEMMv-A on sB ----
    #pragma unroll
    for (int mt = 0; mt < 2; ++mt)
      #pragma unroll
      for (int nt = 0; nt < 5; ++nt){
        int col = wave*80 + nt*16 + r;
        if (col >= 384){
          int mm = col - 384, ch = mm & 127;
          #pragma unroll
          for (int i = 0; i < 4; ++i){
            int row = mt*16 + kg*4 + i;
            float g = accg[mt][nt][i];
            float gm = (mm >= 128) ? 1.4142135623730951f * sS[row*128 + ch] * g : g;
            #pragma unroll
            for (int d = 0; d < 3; ++d){
              float val = sV[row*384 + d*128 + ch] * gm;
              sA[swz256(d*32 + row, mm)] = (_Float16)(val - (float)(_Float16)val);
            }
          }
        }
      }

    floatx4 accv[6];
    #pragma unroll
    for (int i = 0; i < 6; ++i) accv[i] = (floatx4){0.f,0.f,0.f,0.f};
    gvcore<2>(sB, WVp, wave*16, accv, r, kg);   // Ah*Bh + Ah*Bl
    __syncthreads();                            // B5

    // ---- phase 5: GEMMv-B on sA (Al*Bh) ----
    gvcore<1>(sA, WVp, wave*16, accv, r, kg);
    __syncthreads();                            // B6

    // ---- dump OS -> sB(f32), OV -> sA(f32) ----
    #pragma unroll
    for (int ct = 0; ct < 2; ++ct)
      #pragma unroll
      for (int i = 0; i < 4; ++i){
        int row = (wave&1)*16 + kg*4 + i;
        int col = (wave>>1)*32 + ct*16 + r;
        OSf[row*128 + col] = acc0[0][ct][i];
      }
    #pragma unroll
    for (int rp = 0; rp < 6; ++rp)
      #pragma unroll
      for (int i = 0; i < 4; ++i){
        int r4 = rp*16 + kg*4 + i;
        int col = wave*16 + r;
        OVf[r4*128 + col] = accv[rp][i];
      }
    __syncthreads();                            // B7

    // ---- P7a: residual reads ----
    float sacc[8], vacc[24];
    float ssum = 0.f;
    #pragma unroll
    for (int q = 0; q < 8; ++q){
      int c = j16 + q*16;
      sacc[q] = sS[row16*128 + c] + OSf[row16*128 + c];
      ssum += sacc[q];
    }
    #pragma unroll
    for (int q = 0; q < 24; ++q){
      int e = j16 + q*16;
      int d = e >> 7, ch = e & 127;
      vacc[q] = sV[row16*384 + e] + OVf[(d*32 + row16)*128 + ch];
    }
    __syncthreads();                            // B8

    // ---- P7b: (l=0) eq-LN + next sc' | (l=1) final output ----
    if (l == 0){
      float mu = red16(ssum) * (1.0f/128.0f);
      float var = 0.f;
      #pragma unroll
      for (int q = 0; q < 8; ++q){ float d = sacc[q] - mu; var += d*d; }
      var = red16(var) * (1.0f/128.0f);
      float sd = sqrtf(var + 1e-6f);
      float v2 = 0.f;
      #pragma unroll
      for (int q = 0; q < 24; ++q) v2 += vacc[q]*vacc[q];
      float rms = sqrtf(red16(v2) * (1.0f/384.0f) + 1e-6f);
      float ns[8], nv[24];
      #pragma unroll
      for (int q = 0; q < 8; ++q){
        int c = j16 + q*16;
        ns[q] = (sacc[q] - mu) / sd * g0[c];
        sS[row16*128 + c] = ns[q];
      }
      #pragma unroll
      for (int q = 0; q < 24; ++q){
        int e = j16 + q*16;
        nv[q] = vacc[q] / rms * g1[e & 127];
        sV[row16*384 + e] = nv[q];
      }
      #pragma unroll
      for (int q = 0; q < 24; ++q){
        int c = j16 + q*16;
        float val;
        if (c < 128) val = ns[q];
        else if (c < 256) val = ns[q-8]*ns[q-8];
        else {
          int t = q - 16;
          val = (nv[t]*nv[t] + nv[t+8]*nv[t+8] + nv[t+16]*nv[t+16])
                * 0.5773502691896258f;
        }
        split2(val, &sA[swzA(row16, c)], &sA[swzA(row16, 384 + c)]);
      }
    } else {
      size_t ob = (size_t)(row0g + row16)*512;
      #pragma unroll
      for (int q = 0; q < 8; ++q){
        int c = j16 + q*16;
        out[ob + c] = sacc[q];
      }
      #pragma unroll
      for (int q = 0; q < 24; ++q){
        int e = j16 + q*16;
        int d = e >> 7, ch = e & 127;
        out[ob + 128 + ch*3 + d] = vacc[q];
      }
    }
    __syncthreads();                            // B9
  }
}

// ---------------------------- host launcher --------------------------------

extern "C" void kernel_launch(void* const* d_in, const int* in_sizes, int n_in,
                              void* d_out, int out_size, void* d_ws, size_t ws_size,
                              hipStream_t stream){
  const float* x  = (const float*)d_in[0];
  const float* w1 = (const float*)d_in[1];
  const float* w2 = (const float*)d_in[2];
  const float* w0 = (const float*)d_in[3];
  const float* wv = (const float*)d_in[4];
  const float* g0 = (const float*)d_in[5];
  const float* g1 = (const float*)d_in[6];
  float* out = (float*)d_out;
  const int N = in_sizes[0] / 512;                 // 16384

  _Float16* W = (_Float16*)d_ws;                   // 2 x 950272 halves = 3.8 MB

  prep_all2<<<cdiv_h(950272,256),256,0,stream>>>(w1, w2, w0, wv, W);
  fused<<<N/32, NTHR, 163840, stream>>>(x, W, g0, g1, out);
}